// Round 6
// baseline (60.936 us; speedup 1.0000x reference)
//
#include <hip/hip_runtime.h>
#include <math.h>

// Problem constants (from reference):
constexpr int Bn = 1024;
constexpr int S  = 512;
constexpr int H  = 768;
constexpr int D1 = 128;
constexpr int HV = H / 4;     // 192 float4 per feature row

constexpr int NSUB = 32;      // 48-row d-subchunks in head
constexpr int DSUB = (2 * H) / NSUB;  // 48

// ws layout (floats):
//   cls [Bn][768]      — CLS features
//   gp  [2][Bn][768]   — span-mean partials (even/odd rows), pre-scaled by 1/len
//   P   [Bn][NSUB][D1] — per-subchunk partial h dots (16 MB)

// Kernel 1 (identical to round-2 measured best): ragged span mean-pool,
// 2 blocks/example (even/odd rows); 4 independent loads in flight/wave.
__global__ __launch_bounds__(192) void pool_partial(
    const float* __restrict__ feat, const int* __restrict__ start,
    const int* __restrict__ endp, float* __restrict__ cls,
    float* __restrict__ gp) {
  const int b = blockIdx.x >> 1;
  const int p = blockIdx.x & 1;
  const int t = threadIdx.x;  // one float4 column
  const float4* base = reinterpret_cast<const float4*>(feat) + (size_t)b * (S * HV);

  if (p == 0) {
    reinterpret_cast<float4*>(cls)[(size_t)b * HV + t] = base[t];  // CLS row
  }

  const int s0 = start[b];
  const int s1 = endp[b];
  float4 a0{0,0,0,0}, a1{0,0,0,0}, a2{0,0,0,0}, a3{0,0,0,0};
  int s = s0 + p;
  for (; s + 6 < s1; s += 8) {
    float4 v0 = base[(size_t)(s    ) * HV + t];
    float4 v1 = base[(size_t)(s + 2) * HV + t];
    float4 v2 = base[(size_t)(s + 4) * HV + t];
    float4 v3 = base[(size_t)(s + 6) * HV + t];
    a0.x += v0.x; a0.y += v0.y; a0.z += v0.z; a0.w += v0.w;
    a1.x += v1.x; a1.y += v1.y; a1.z += v1.z; a1.w += v1.w;
    a2.x += v2.x; a2.y += v2.y; a2.z += v2.z; a2.w += v2.w;
    a3.x += v3.x; a3.y += v3.y; a3.z += v3.z; a3.w += v3.w;
  }
  for (; s < s1; s += 2) {
    float4 v = base[(size_t)s * HV + t];
    a0.x += v.x; a0.y += v.y; a0.z += v.z; a0.w += v.w;
  }
  const float inv = 1.0f / (float)(s1 - s0);
  float4 r;
  r.x = ((a0.x + a1.x) + (a2.x + a3.x)) * inv;
  r.y = ((a0.y + a1.y) + (a2.y + a3.y)) * inv;
  r.z = ((a0.z + a1.z) + (a2.z + a3.z)) * inv;
  r.w = ((a0.w + a1.w) + (a2.w + a3.w)) * inv;
  reinterpret_cast<float4*>(gp)[((size_t)p * Bn + b) * HV + t] = r;
}

// g loader: CLS chunks read cls only; CRC chunks read+sum the two partials.
template <bool CLS>
__device__ __forceinline__ float4 load_g(const float* a, const float* b, int j) {
  float4 u = reinterpret_cast<const float4*>(a)[j];
  if (!CLS) {
    float4 v = reinterpret_cast<const float4*>(b)[j];
    u.x += v.x; u.y += v.y; u.z += v.z; u.w += v.w;
  }
  return u;
}

// Head inner: 12 groups of 4 d's. Per group: 4 coalesced W1 float4 loads
// (512 B unique/wave; half-wave duplication merges in the coalescer) +
// 4 broadcast g loads + 64 FMA wave-inst (128 cy) -> VALU/L2-balanced.
template <bool CLS>
__device__ __forceinline__ void head_loop(
    const float4* __restrict__ Wv, const float* ga0, const float* ga1,
    const float* ga2, const float* ga3, const float* gb0, const float* gb1,
    const float* gb2, const float* gb3, float4 acc[4]) {
  #pragma unroll 4
  for (int grp = 0; grp < DSUB / 4; ++grp) {
    const int dd = grp * 4;
    float4 w0 = Wv[(size_t)(dd + 0) * 32];
    float4 w1 = Wv[(size_t)(dd + 1) * 32];
    float4 w2 = Wv[(size_t)(dd + 2) * 32];
    float4 w3 = Wv[(size_t)(dd + 3) * 32];
    float4 g0 = load_g<CLS>(ga0, gb0, grp);
    float4 g1 = load_g<CLS>(ga1, gb1, grp);
    float4 g2 = load_g<CLS>(ga2, gb2, grp);
    float4 g3 = load_g<CLS>(ga3, gb3, grp);
    #define ACCUM(i, gv)                                                   \
      acc[i].x += gv.x * w0.x + gv.y * w1.x + gv.z * w2.x + gv.w * w3.x;   \
      acc[i].y += gv.x * w0.y + gv.y * w1.y + gv.z * w2.y + gv.w * w3.y;   \
      acc[i].z += gv.x * w0.z + gv.y * w1.z + gv.z * w2.z + gv.w * w3.z;   \
      acc[i].w += gv.x * w0.w + gv.y * w1.w + gv.z * w2.w + gv.w * w3.w;
    ACCUM(0, g0) ACCUM(1, g1) ACCUM(2, g2) ACCUM(3, g3)
    #undef ACCUM
  }
}

// Kernel 2: partial W1 dots. Wave = 8 examples x 48-d subchunk.
// Lane = (eh = l>>5, kq = l&31); thread tile = 4 examples x 4 k's.
// Grid 2048 x 128 thr -> 16 waves/CU. No LDS, no barriers.
__global__ __launch_bounds__(128) void head_partial(
    const float* __restrict__ cls, const float* __restrict__ gp,
    const float* __restrict__ W1, float* __restrict__ P) {
  const int t   = threadIdx.x;
  const int l   = t & 63;
  const int w   = t >> 6;
  const int eg  = blockIdx.x >> 4;        // 0..127
  const int dp  = blockIdx.x & 15;        // 0..15
  const int sub = dp * 2 + w;             // 0..31
  const int d0  = sub * DSUB;
  const int kq  = l & 31;                 // k-quad: k = kq*4
  const int eh  = l >> 5;
  const int ebase = eg * 8 + eh * 4;      // first of this thread's 4 examples

  const float4* Wv = reinterpret_cast<const float4*>(W1 + (size_t)d0 * D1) + kq;

  float4 acc[4];
  #pragma unroll
  for (int i = 0; i < 4; ++i) acc[i] = make_float4(0.f, 0.f, 0.f, 0.f);

  if (d0 < H) {
    const float* ga0 = cls + (size_t)(ebase + 0) * H + d0;
    const float* ga1 = cls + (size_t)(ebase + 1) * H + d0;
    const float* ga2 = cls + (size_t)(ebase + 2) * H + d0;
    const float* ga3 = cls + (size_t)(ebase + 3) * H + d0;
    head_loop<true>(Wv, ga0, ga1, ga2, ga3, ga0, ga1, ga2, ga3, acc);
  } else {
    const int dd0 = d0 - H;
    const float* ga0 = gp + (size_t)(ebase + 0) * H + dd0;
    const float* ga1 = gp + (size_t)(ebase + 1) * H + dd0;
    const float* ga2 = gp + (size_t)(ebase + 2) * H + dd0;
    const float* ga3 = gp + (size_t)(ebase + 3) * H + dd0;
    const size_t off = (size_t)Bn * H;
    head_loop<false>(Wv, ga0, ga1, ga2, ga3,
                     ga0 + off, ga1 + off, ga2 + off, ga3 + off, acc);
  }

  #pragma unroll
  for (int i = 0; i < 4; ++i) {
    reinterpret_cast<float4*>(
        P + ((size_t)(ebase + i) * NSUB + sub) * D1)[kq] = acc[i];
  }
}

// Kernel 3: combine subchunks, relu, dot W2, sigmoid. One wave per example.
__global__ __launch_bounds__(256) void finalize(
    const float* __restrict__ P, const float* __restrict__ b1,
    const float* __restrict__ W2, const float* __restrict__ b2,
    float* __restrict__ out) {
  const int t = threadIdx.x;
  const int w = t >> 6, l = t & 63;
  const int e = blockIdx.x * 4 + w;
  const int k0 = l, k1 = l + 64;
  const float* Pe = P + (size_t)e * NSUB * D1;
  float h0 = b1[k0], h1 = b1[k1];
  #pragma unroll 8
  for (int c = 0; c < NSUB; ++c) {
    h0 += Pe[c * D1 + k0];
    h1 += Pe[c * D1 + k1];
  }
  h0 = fmaxf(h0, 0.f); h1 = fmaxf(h1, 0.f);
  float v = h0 * W2[k0] + h1 * W2[k1];
  #pragma unroll
  for (int off = 32; off > 0; off >>= 1) v += __shfl_down(v, off);
  if (l == 0) out[e] = 1.0f / (1.0f + expf(-(v + b2[0])));
}

extern "C" void kernel_launch(void* const* d_in, const int* in_sizes, int n_in,
                              void* d_out, int out_size, void* d_ws, size_t ws_size,
                              hipStream_t stream) {
  const float* feat = (const float*)d_in[0];   // [B,S,H] fp32
  const int* start  = (const int*)d_in[1];     // [B]
  const int* endp   = (const int*)d_in[2];     // [B]
  const float* W1   = (const float*)d_in[3];   // [2H,D1]
  const float* b1   = (const float*)d_in[4];   // [D1]
  const float* W2   = (const float*)d_in[5];   // [D1,1]
  const float* b2   = (const float*)d_in[6];   // [1]
  float* out = (float*)d_out;                  // [B]

  float* wsf = (float*)d_ws;
  float* cls = wsf;                            // [Bn][768]
  float* gp  = cls + (size_t)Bn * H;           // [2][Bn][768]
  float* P   = gp + (size_t)2 * Bn * H;        // [Bn][NSUB][D1]

  hipLaunchKernelGGL(pool_partial, dim3(Bn * 2), dim3(192), 0, stream,
                     feat, start, endp, cls, gp);
  hipLaunchKernelGGL(head_partial, dim3((Bn / 8) * (NSUB / 2)), dim3(128), 0,
                     stream, cls, gp, W1, P);
  hipLaunchKernelGGL(finalize, dim3(Bn / 4), dim3(256), 0, stream,
                     P, b1, W2, b2, out);
}